// Round 3
// baseline (403.244 us; speedup 1.0000x reference)
//
#include <hip/hip_runtime.h>
#include <hip/hip_cooperative_groups.h>
#include <stdint.h>
#include <math.h>

namespace cg = cooperative_groups;

// Problem constants
#define NN   20000
#define EE   320000
#define HH   128
#define MSTR 136            // h1/mij LDS row stride (u16)

typedef __attribute__((ext_vector_type(8)))  short          bf16x8;
typedef __attribute__((ext_vector_type(4)))  float          f32x4;
typedef __attribute__((ext_vector_type(16))) float          f32x16;
typedef unsigned short u16;
typedef unsigned int   u32;

// fp32 -> bf16 round-to-nearest-even
__device__ __forceinline__ u16 f2b(float f) {
  union { float f; unsigned int u; } v; v.f = f;
  return (u16)((v.u + 0x7fffu + ((v.u >> 16) & 1u)) >> 16);
}
__device__ __forceinline__ float b2f(unsigned int x) {
  union { float f; unsigned int u; } v; v.u = x << 16;
  return v.f;
}
__device__ __forceinline__ bf16x8 cvt8(float4 a, float4 b) {
  bf16x8 r;
  r[0] = (short)f2b(a.x); r[1] = (short)f2b(a.y);
  r[2] = (short)f2b(a.z); r[3] = (short)f2b(a.w);
  r[4] = (short)f2b(b.x); r[5] = (short)f2b(b.y);
  r[6] = (short)f2b(b.z); r[7] = (short)f2b(b.w);
  return r;
}
__device__ __forceinline__ bf16x8 pack8(const float* v) {
  bf16x8 r;
  #pragma unroll
  for (int j = 0; j < 8; ++j) r[j] = (short)f2b(v[j]);
  return r;
}

// packed bf16x2 atomic add (CDNA4 global_atomic_pk_add_bf16), fire-and-forget
__device__ __forceinline__ void pk_atomic_bf16(u16* addr, unsigned int data) {
  asm volatile("global_atomic_pk_add_bf16 %0, %1, off"
               :
               : "v"((unsigned long long)(uintptr_t)addr), "v"(data)
               : "memory");
}

// ---------------------------------------------------------------------------
// prep: (a) zero mi+dx+hist, (b) h -> bf16 (hb, node_kernel only),
// (c) pack weights to bf16.
// 32-style (edge GEMMs, mfma 32x32x16): n = nt*32+(l&31), k = kc*16+(l>>5)*8+j
// 16-style (node GEMMs, mfma 16x16x32): n = nt*16+(l&15), k = kc*32+(l>>4)*8+j
// ew1 K-rows permuted to feat order (hi | hj | attr+rbf | pad).
// ---------------------------------------------------------------------------
__global__ void prep_kernel(const float* __restrict__ h,
                            const float* __restrict__ ew1, const float* __restrict__ ew2,
                            const float* __restrict__ xw1, const float* __restrict__ nw1,
                            const float* __restrict__ nw2,
                            u16* __restrict__ ew1c, u16* __restrict__ ew2c,
                            u16* __restrict__ xw1c, u16* __restrict__ nw1c,
                            u16* __restrict__ nw2c, float4* __restrict__ zbase,
                            u16* __restrict__ hb) {
  int idx = blockIdx.x * 256 + threadIdx.x;

  // zero mi (5120000 B) + dx (240000 B) + hist (80000 B) = 340000 float4s
  float4 z4 = {0.f, 0.f, 0.f, 0.f};
  #pragma unroll
  for (int i = 0; i < 3; ++i) {
    int j = idx + i * 122880;
    if (j < 340000) zbase[j] = z4;
  }
  // h -> bf16: 2,560,000 elems = 320,000 chunks of 8
  #pragma unroll
  for (int i = 0; i < 3; ++i) {
    int c = idx + i * 122880;
    if (c < 320000) {
      float4 a = *(const float4*)&h[(size_t)c * 8];
      float4 b = *(const float4*)&h[(size_t)c * 8 + 4];
      *(bf16x8*)&hb[(size_t)c * 8] = cvt8(a, b);
    }
  }

  int i2, style;
  u16* dst;
  const float* src;
  if (idx < 40960)       { i2 = idx;          dst = ew1c; src = ew1; style = 1; }
  else if (idx < 57344)  { i2 = idx - 40960;  dst = ew2c; src = ew2; style = 1; }
  else if (idx < 73728)  { i2 = idx - 57344;  dst = xw1c; src = xw1; style = 1; }
  else if (idx < 106496) { i2 = idx - 73728;  dst = nw1c; src = nw1; style = 0; }
  else if (idx < 122880) { i2 = idx - 106496; dst = nw2c; src = nw2; style = 0; }
  else return;

  int n, k;
  if (style) {
    int kc = i2 >> 11, rem = i2 & 2047, nt = rem >> 9, rem2 = rem & 511;
    int l = rem2 >> 3, j = rem2 & 7;
    n = nt * 32 + (l & 31);
    k = kc * 16 + (l >> 5) * 8 + j;
  } else {
    int kc = i2 >> 12, rem = i2 & 4095, nt = rem >> 9, rem2 = rem & 511;
    int l = rem2 >> 3, j = rem2 & 7;
    n = nt * 16 + (l & 15);
    k = kc * 32 + (l >> 4) * 8 + j;
  }
  float v;
  if (dst == ew1c) {
    if (k < 256)      v = src[(k + 48) * HH + n];   // hi|hj block
    else if (k < 304) v = src[(k - 256) * HH + n];  // attr|rbf block
    else              v = 0.0f;                     // pad (kc 19, unused)
  } else {
    v = src[k * HH + n];
  }
  dst[i2] = f2b(v);
}

// ---------------------------------------------------------------------------
// ONE cooperative kernel replaces hist/scan/scatter (3 launches -> 1; the
// R1 bench showed ~10us/launch overhead dominated the sort's ~12us of work).
// 250 blocks x 256 thr: P1 hist -> P2 hierarchical exclusive scan (80
// bins/block) -> P3 scatter writing packed uint2 {dst | src<<15, eid} so the
// edge kernel gets all per-row state with ONE 8-B sequential load.
// ---------------------------------------------------------------------------
__global__ __launch_bounds__(256) void sort_kernel(
    const int* __restrict__ edge_index,
    u32* __restrict__ hist,      // pre-zeroed by prep
    u32* __restrict__ partials,  // 256 u32 scratch
    u32* __restrict__ cursor,    // 20000
    uint2* __restrict__ esr) {   // 320000 packed records
  cg::grid_group grid = cg::this_grid();
  const int t = threadIdx.x, b = blockIdx.x;
  const int tid = b * 256 + t;             // 0..63999

  // P1: histogram
  #pragma unroll
  for (int k = 0; k < 5; ++k) {
    int e = tid + k * 64000;
    atomicAdd(&hist[edge_index[e]], 1u);
  }
  grid.sync();

  // P2a: per-block exclusive scan of 80 bins
  __shared__ u32 lh[80];
  if (t < 80) lh[t] = hist[b * 80 + t];
  __syncthreads();
  if (t == 0) {
    u32 s = 0;
    for (int i = 0; i < 80; ++i) { u32 c = lh[i]; lh[i] = s; s += c; }
    partials[b] = s;
  }
  grid.sync();

  // P2b: scan the 250 block sums (tiny, serial)
  if (tid == 0) {
    u32 s = 0;
    for (int i = 0; i < 250; ++i) { u32 c = partials[i]; partials[i] = s; s += c; }
  }
  grid.sync();

  // P2c: global exclusive prefix per dst
  if (t < 80) cursor[b * 80 + t] = partials[b] + lh[t];
  grid.sync();

  // P3: scatter packed records into dst-sorted slots
  #pragma unroll
  for (int k = 0; k < 5; ++k) {
    int e = tid + k * 64000;
    int d = edge_index[e];
    int s = edge_index[EE + e];
    u32 p = atomicAdd(&cursor[d], 1u);
    esr[p] = make_uint2((u32)d | ((u32)s << 15), (u32)e);
  }
}

// ---------------------------------------------------------------------------
// edge kernel: 128 dst-sorted slots/block, 4 waves, wave owns 32 rows x 128
// cols, mfma 32x32x16. NOW BARRIER-FREE: each lane loads its row's packed
// record (8 B sequential) and all LDS traffic is wave-private (dst_s/relx_s/
// h1_s band, eij_s/xg_s per-wave), so the 4 waves run fully decoupled —
// phase diversity instead of lockstep gather stalls. launch_bounds(256,4):
// 4 blocks/CU (LDS 38400*4=153.6K fits; needs <=64 arch VGPR + 64 acc).
// mi/dx: fp32 run-aggregation over sorted runs, ~1 pk-atomic burst per run.
// ---------------------------------------------------------------------------
__global__ __launch_bounds__(256, 4) void edge_kernel(
    const float* __restrict__ h, const float* __restrict__ x,
    const float* __restrict__ edge_attr,
    const u16* __restrict__ ew1c, const float* __restrict__ eb1,
    const u16* __restrict__ ew2c, const float* __restrict__ eb2,
    const float* __restrict__ inf_w, const float* __restrict__ inf_b,
    const u16* __restrict__ xw1c, const float* __restrict__ xb1,
    const float* __restrict__ xw2, const float* __restrict__ xb2,
    const uint2* __restrict__ esr,
    u16* __restrict__ mi, float* __restrict__ dx) {
  __shared__ u16 h1_s[128 * MSTR];     // 34816 B: GEMM1 out, then mij overlay
  __shared__ float relx_s[128][4];     //  2048 B
  __shared__ int dst_s[128];           //   512 B
  __shared__ float eij_s[4][32];       //   512 B
  __shared__ float xg_s[4][32];        //   512 B

  const int t   = threadIdx.x;
  const int w   = t >> 6;
  const int l   = t & 63;
  const int l31 = l & 31;
  const int hh  = l >> 5;              // k-half
  const int e0  = blockIdx.x * 128;
  const int myrow = w * 32 + l31;      // local row 0..127

  // ---- phase A (barrier-free): per-lane packed record + rel_x ----
  uint2 rec = esr[e0 + myrow];
  const int dstv = (int)(rec.x & 0x7FFFu);
  const int srcv = (int)((rec.x >> 15) & 0x7FFFu);
  const int eid  = (int)rec.y;

  float rx = x[dstv * 3 + 0] - x[srcv * 3 + 0];
  float ry = x[dstv * 3 + 1] - x[srcv * 3 + 1];
  float rz = x[dstv * 3 + 2] - x[srcv * 3 + 2];
  const float dn = sqrtf(rx * rx + ry * ry + rz * rz);
  if (hh == 0) {
    dst_s[myrow] = dstv;
    relx_s[myrow][0] = rx; relx_s[myrow][1] = ry;
    relx_s[myrow][2] = rz; relx_s[myrow][3] = dn;
  }
  // no __syncthreads(): all later LDS reads are of this wave's own band;
  // per-wave LDS ordering + compiler lgkmcnt waits cover the RAW deps.

  f32x16 acc[4];
  #pragma unroll
  for (int nt = 0; nt < 4; ++nt)
    #pragma unroll
    for (int i = 0; i < 16; ++i) acc[nt][i] = 0.f;

  // ---- GEMM1 phase hi (feat k 0..127 = h[dst]; sorted -> few rows/wave) ----
  {
    const float* hp = h + (size_t)dstv * HH;
    bf16x8 af[8];
    #pragma unroll
    for (int kc = 0; kc < 8; ++kc) {
      float4 a0 = *(const float4*)&hp[kc * 16 + hh * 8];
      float4 a1 = *(const float4*)&hp[kc * 16 + hh * 8 + 4];
      af[kc] = cvt8(a0, a1);
    }
    #pragma unroll
    for (int kc = 0; kc < 8; ++kc) {
      const u16* bp = ew1c + (kc * 4) * 512 + l * 8;
      #pragma unroll
      for (int nt = 0; nt < 4; ++nt) {
        bf16x8 b = *(const bf16x8*)(bp + nt * 512);
        acc[nt] = __builtin_amdgcn_mfma_f32_32x32x16_bf16(af[kc], b, acc[nt], 0, 0, 0);
      }
    }
  }
  // ---- GEMM1 phase hj (feat k 128..255 = h[src]) ----
  {
    const float* hp = h + (size_t)srcv * HH;
    bf16x8 af[8];
    #pragma unroll
    for (int kc = 0; kc < 8; ++kc) {
      float4 a0 = *(const float4*)&hp[kc * 16 + hh * 8];
      float4 a1 = *(const float4*)&hp[kc * 16 + hh * 8 + 4];
      af[kc] = cvt8(a0, a1);
    }
    #pragma unroll
    for (int kc = 0; kc < 8; ++kc) {
      const u16* bp = ew1c + ((8 + kc) * 4) * 512 + l * 8;
      #pragma unroll
      for (int nt = 0; nt < 4; ++nt) {
        bf16x8 b = *(const bf16x8*)(bp + nt * 512);
        acc[nt] = __builtin_amdgcn_mfma_f32_32x32x16_bf16(af[kc], b, acc[nt], 0, 0, 0);
      }
    }
  }
  // ---- GEMM1 phase attr+rbf (feat k 256..303; kc 16..18) ----
  {
    const float step  = 100.0f / 19.0f;
    const float coeff = -0.5f / (step * step);
    const float* ap   = edge_attr + (size_t)eid * 28;
    float v0[8], v1[8], v2[8];
    if (hh == 0) {
      float4 a0 = *(const float4*)&ap[0],  a1 = *(const float4*)&ap[4];
      float4 a2 = *(const float4*)&ap[16], a3 = *(const float4*)&ap[20];
      v0[0]=a0.x; v0[1]=a0.y; v0[2]=a0.z; v0[3]=a0.w;
      v0[4]=a1.x; v0[5]=a1.y; v0[6]=a1.z; v0[7]=a1.w;
      v1[0]=a2.x; v1[1]=a2.y; v1[2]=a2.z; v1[3]=a2.w;
      v1[4]=a3.x; v1[5]=a3.y; v1[6]=a3.z; v1[7]=a3.w;
      #pragma unroll
      for (int j = 0; j < 8; ++j) {           // rbf 4..11
        float dd = dn - (float)(4 + j) * step;
        v2[j] = __expf(coeff * dd * dd);
      }
    } else {
      float4 a0 = *(const float4*)&ap[8],  a1 = *(const float4*)&ap[12];
      float4 a2 = *(const float4*)&ap[24];
      v0[0]=a0.x; v0[1]=a0.y; v0[2]=a0.z; v0[3]=a0.w;
      v0[4]=a1.x; v0[5]=a1.y; v0[6]=a1.z; v0[7]=a1.w;
      v1[0]=a2.x; v1[1]=a2.y; v1[2]=a2.z; v1[3]=a2.w;
      #pragma unroll
      for (int j = 0; j < 4; ++j) {           // rbf 0..3
        float dd = dn - (float)j * step;
        v1[4 + j] = __expf(coeff * dd * dd);
      }
      #pragma unroll
      for (int j = 0; j < 8; ++j) {           // rbf 12..19
        float dd = dn - (float)(12 + j) * step;
        v2[j] = __expf(coeff * dd * dd);
      }
    }
    bf16x8 afr[3];
    afr[0] = pack8(v0); afr[1] = pack8(v1); afr[2] = pack8(v2);
    #pragma unroll
    for (int kc = 0; kc < 3; ++kc) {
      const u16* bp = ew1c + ((16 + kc) * 4) * 512 + l * 8;
      #pragma unroll
      for (int nt = 0; nt < 4; ++nt) {
        bf16x8 b = *(const bf16x8*)(bp + nt * 512);
        acc[nt] = __builtin_amdgcn_mfma_f32_32x32x16_bf16(afr[kc], b, acc[nt], 0, 0, 0);
      }
    }
  }
  // ---- GEMM1 epilogue: relu(+eb1) -> h1_s (wave-private rows) ----
  #pragma unroll
  for (int nt = 0; nt < 4; ++nt) {
    float bb = eb1[nt * 32 + l31];
    #pragma unroll
    for (int i = 0; i < 16; ++i) {
      float v = acc[nt][i] + bb; v = v > 0.f ? v : 0.f;
      int row = (i & 3) + 8 * (i >> 2) + 4 * hh;
      h1_s[(w * 32 + row) * MSTR + nt * 32 + l31] = f2b(v);
    }
  }

  // ---- GEMM2: A = h1 (own band, no barrier), B = ew2c ----
  bf16x8 a2[8];
  #pragma unroll
  for (int kc = 0; kc < 8; ++kc)
    a2[kc] = *(const bf16x8*)&h1_s[myrow * MSTR + kc * 16 + hh * 8];
  #pragma unroll
  for (int nt = 0; nt < 4; ++nt)
    #pragma unroll
    for (int i = 0; i < 16; ++i) acc[nt][i] = 0.f;
  #pragma unroll
  for (int kc = 0; kc < 8; ++kc) {
    const u16* bp = ew2c + (kc * 4) * 512 + l * 8;
    #pragma unroll
    for (int nt = 0; nt < 4; ++nt) {
      bf16x8 b = *(const bf16x8*)(bp + nt * 512);
      acc[nt] = __builtin_amdgcn_mfma_f32_32x32x16_bf16(a2[kc], b, acc[nt], 0, 0, 0);
    }
  }
  // ---- GEMM2 epilogue: mij = relu(+eb2) -> h1_s overlay; eij partials ----
  float p[16];
  #pragma unroll
  for (int i = 0; i < 16; ++i) p[i] = 0.f;
  #pragma unroll
  for (int nt = 0; nt < 4; ++nt) {
    float bb = eb2[nt * 32 + l31];
    float iw = inf_w[nt * 32 + l31];
    #pragma unroll
    for (int i = 0; i < 16; ++i) {
      float v = acc[nt][i] + bb; v = v > 0.f ? v : 0.f;
      p[i] += v * iw;
      int row = (i & 3) + 8 * (i >> 2) + 4 * hh;
      h1_s[(w * 32 + row) * MSTR + nt * 32 + l31] = f2b(v);
    }
  }
  // eij: reduce over 32 cols (xor, width 32), sigmoid; stash per-row to LDS
  {
    float ib = inf_b[0];
    #pragma unroll
    for (int m = 1; m < 32; m <<= 1)
      #pragma unroll
      for (int i = 0; i < 16; ++i) p[i] += __shfl_xor(p[i], m, 32);
    #pragma unroll
    for (int i = 0; i < 16; ++i)
      p[i] = 1.0f / (1.0f + __expf(-(p[i] + ib)));   // p = eij per row-slot
    if (l31 == 0) {
      #pragma unroll
      for (int i = 0; i < 16; ++i) {
        int row = (i & 3) + 8 * (i >> 2) + 4 * hh;
        eij_s[w][row] = p[i];
      }
    }
  }

  // ---- GEMM3: A = mij (own band), B = xw1c ----
  bf16x8 a3[8];
  #pragma unroll
  for (int kc = 0; kc < 8; ++kc)
    a3[kc] = *(const bf16x8*)&h1_s[myrow * MSTR + kc * 16 + hh * 8];
  #pragma unroll
  for (int nt = 0; nt < 4; ++nt)
    #pragma unroll
    for (int i = 0; i < 16; ++i) acc[nt][i] = 0.f;
  #pragma unroll
  for (int kc = 0; kc < 8; ++kc) {
    const u16* bp = xw1c + (kc * 4) * 512 + l * 8;
    #pragma unroll
    for (int nt = 0; nt < 4; ++nt) {
      bf16x8 b = *(const bf16x8*)(bp + nt * 512);
      acc[nt] = __builtin_amdgcn_mfma_f32_32x32x16_bf16(a3[kc], b, acc[nt], 0, 0, 0);
    }
  }
  // ---- xg = relu(+xb1) @ xw2 + xb2, reduced over cols; stash to LDS ----
  float p2[16];
  #pragma unroll
  for (int i = 0; i < 16; ++i) p2[i] = 0.f;
  #pragma unroll
  for (int nt = 0; nt < 4; ++nt) {
    float bb = xb1[nt * 32 + l31];
    float xv = xw2[nt * 32 + l31];
    #pragma unroll
    for (int i = 0; i < 16; ++i) {
      float v = acc[nt][i] + bb; v = v > 0.f ? v : 0.f;
      p2[i] += v * xv;
    }
  }
  {
    float xb2_0 = xb2[0];
    #pragma unroll
    for (int m = 1; m < 32; m <<= 1)
      #pragma unroll
      for (int i = 0; i < 16; ++i) p2[i] += __shfl_xor(p2[i], m, 32);
    #pragma unroll
    for (int i = 0; i < 16; ++i) p2[i] += xb2_0;
    if (l31 == 0) {
      #pragma unroll
      for (int i = 0; i < 16; ++i) {
        int row = (i & 3) + 8 * (i >> 2) + 4 * hh;
        xg_s[w][row] = p2[i];
      }
    }
  }

  // ---- mi: run-aggregated flush over the wave's own 32 sorted rows. Lane
  // owns col-pair (2l,2l+1); fp32-accumulate bf16(mij)*eij per equal-dst run;
  // one pk-atomic burst per run boundary (wave-uniform branch). r==31 always
  // flushes, so no cross-band LDS read (barrier-free safe). ----
  {
    float s0 = 0.f, s1 = 0.f;
    for (int r = 0; r < 32; ++r) {
      int gr = w * 32 + r;
      unsigned int pr = *(const unsigned int*)&h1_s[gr * MSTR + 2 * l];
      float e = eij_s[w][r];
      s0 += b2f(pr & 0xffffu) * e;
      s1 += b2f(pr >> 16) * e;
      bool flush = (r == 31) || (dst_s[gr + 1] != dst_s[gr]);
      if (flush) {
        unsigned int packed = (unsigned int)f2b(s0) | ((unsigned int)f2b(s1) << 16);
        pk_atomic_bf16(mi + (size_t)dst_s[gr] * HH + 2 * l, packed);
        s0 = 0.f; s1 = 0.f;
      }
    }
  }
  // ---- dx: run-aggregated, 3 lanes/wave scan own band ----
  if (l < 3) {
    float sd = 0.f;
    for (int r = 0; r < 32; ++r) {
      int gr = w * 32 + r;
      sd += relx_s[gr][l] * xg_s[w][r];
      if (r == 31 || dst_s[gr + 1] != dst_s[gr]) {
        atomicAdd(&dx[(size_t)dst_s[gr] * 3 + l], sd);
        sd = 0.f;
      }
    }
  }
}

// ---------------------------------------------------------------------------
// node kernel: 16 rows/block, 1250 blocks; waves split N. h read via hb
// (bf16, direct contiguous loads). 16x16x32 MFMA.
// ---------------------------------------------------------------------------
__global__ __launch_bounds__(256, 6) void node_kernel(
    const u16* __restrict__ hb, const float* __restrict__ x,
    const u16* __restrict__ nw1c, const float* __restrict__ nb1,
    const u16* __restrict__ nw2c, const float* __restrict__ nb2,
    const u16* __restrict__ mi, const float* __restrict__ dx,
    float* __restrict__ out) {
  __shared__ u16 h1_s[16 * MSTR];

  const int t   = threadIdx.x;
  const int w   = t >> 6;
  const int l   = t & 63;
  const int l15 = l & 15;
  const int q   = l >> 4;
  const int r0  = blockIdx.x * 16;
  const int gr  = r0 + l15;

  const u16* mp = mi + (size_t)gr * HH;
  const u16* hp = hb + (size_t)gr * HH;
  bf16x8 afrag[8];
  #pragma unroll
  for (int c = 0; c < 4; ++c) {
    afrag[c]     = *(const bf16x8*)&mp[c * 32 + q * 8];
    afrag[4 + c] = *(const bf16x8*)&hp[c * 32 + q * 8];
  }

  f32x4 acc[2];
  acc[0] = (f32x4){0.f, 0.f, 0.f, 0.f};
  acc[1] = (f32x4){0.f, 0.f, 0.f, 0.f};
  #pragma unroll
  for (int kc = 0; kc < 8; ++kc) {
    const u16* bp = nw1c + (kc << 12) + l * 8;
    #pragma unroll
    for (int i = 0; i < 2; ++i) {
      bf16x8 b = *(const bf16x8*)(bp + (2 * w + i) * 512);
      acc[i] = __builtin_amdgcn_mfma_f32_16x16x32_bf16(afrag[kc], b, acc[i], 0, 0, 0);
    }
  }
  #pragma unroll
  for (int i = 0; i < 2; ++i) {
    int nt = 2 * w + i;
    float b1 = nb1[nt * 16 + l15];
    #pragma unroll
    for (int r = 0; r < 4; ++r) {
      float v = acc[i][r] + b1; v = v > 0.f ? v : 0.f;
      h1_s[(q * 4 + r) * MSTR + nt * 16 + l15] = f2b(v);
    }
  }
  __syncthreads();

  bf16x8 a2[4];
  #pragma unroll
  for (int kc = 0; kc < 4; ++kc)
    a2[kc] = *(const bf16x8*)&h1_s[l15 * MSTR + kc * 32 + q * 8];
  acc[0] = (f32x4){0.f, 0.f, 0.f, 0.f};
  acc[1] = (f32x4){0.f, 0.f, 0.f, 0.f};
  #pragma unroll
  for (int kc = 0; kc < 4; ++kc) {
    const u16* bp = nw2c + (kc << 12) + l * 8;
    #pragma unroll
    for (int i = 0; i < 2; ++i) {
      bf16x8 b = *(const bf16x8*)(bp + (2 * w + i) * 512);
      acc[i] = __builtin_amdgcn_mfma_f32_16x16x32_bf16(a2[kc], b, acc[i], 0, 0, 0);
    }
  }
  #pragma unroll
  for (int i = 0; i < 2; ++i) {
    int nt = 2 * w + i;
    float b2 = nb2[nt * 16 + l15];
    #pragma unroll
    for (int r = 0; r < 4; ++r)
      out[(size_t)(r0 + q * 4 + r) * HH + nt * 16 + l15] = acc[i][r] + b2;
  }
  if (t < 48) {
    int rr = t / 3, dim = t % 3;
    int gr2 = r0 + rr;
    out[(size_t)NN * HH + (size_t)gr2 * 3 + dim] =
        x[(size_t)gr2 * 3 + dim] + dx[(size_t)gr2 * 3 + dim] * (1.0f / (float)EE);
  }
}

// ---------------------------------------------------------------------------
// launch: 4 dispatches (prep, coop sort, edge, node)
// ---------------------------------------------------------------------------
extern "C" void kernel_launch(void* const* d_in, const int* in_sizes, int n_in,
                              void* d_out, int out_size, void* d_ws, size_t ws_size,
                              hipStream_t stream) {
  const float* h         = (const float*)d_in[0];
  const float* x         = (const float*)d_in[1];
  const float* edge_attr = (const float*)d_in[2];
  const float* ew1 = (const float*)d_in[3];
  const float* eb1 = (const float*)d_in[4];
  const float* ew2 = (const float*)d_in[5];
  const float* eb2 = (const float*)d_in[6];
  const float* inf_w = (const float*)d_in[7];
  const float* inf_b = (const float*)d_in[8];
  const float* nw1 = (const float*)d_in[9];
  const float* nb1 = (const float*)d_in[10];
  const float* nw2 = (const float*)d_in[11];
  const float* nb2 = (const float*)d_in[12];
  const float* xw1 = (const float*)d_in[13];
  const float* xb1 = (const float*)d_in[14];
  const float* xw2 = (const float*)d_in[15];
  const float* xb2 = (const float*)d_in[16];
  const int* edge_index = (const int*)d_in[17];
  float* out = (float*)d_out;

  char* wsb = (char*)d_ws;
  u16*   ew1c = (u16*)(wsb + 0);            //   81920 B (32-pack)
  u16*   ew2c = (u16*)(wsb + 81920);        //   32768 B (32-pack)
  u16*   xw1c = (u16*)(wsb + 114688);       //   32768 B (32-pack)
  u16*   nw1c = (u16*)(wsb + 147456);       //   65536 B (16-pack)
  u16*   nw2c = (u16*)(wsb + 212992);       //   32768 B (16-pack)
  u16*   mi   = (u16*)(wsb + 245760);       //  5120000 B (bf16)
  float* dx   = (float*)(wsb + 5365760);    //   240000 B
  u32*   hist = (u32*)(wsb + 5605760);      //    80000 B (zeroed by prep)
  u16*   hb   = (u16*)(wsb + 5685760);      //  5120000 B (bf16 h)
  u32*   cursor   = (u32*)(wsb + 10805760); //    80000 B
  u32*   partials = (u32*)(wsb + 10885760); //     1024 B
  uint2* esr      = (uint2*)(wsb + 10886784); // 2560000 B -> 13446784 total

  // prep zeroes mi+dx+hist and converts h -> hb
  prep_kernel<<<480, 256, 0, stream>>>(
      h, ew1, ew2, xw1, nw1, nw2, ew1c, ew2c, xw1c, nw1c, nw2c,
      (float4*)(wsb + 245760), hb);

  // one cooperative launch: hist + scan + scatter
  {
    void* args[] = {(void*)&edge_index, (void*)&hist, (void*)&partials,
                    (void*)&cursor, (void*)&esr};
    hipLaunchCooperativeKernel((void*)sort_kernel, dim3(250), dim3(256),
                               args, 0, stream);
  }

  edge_kernel<<<EE / 128, 256, 0, stream>>>(
      h, x, edge_attr, ew1c, eb1, ew2c, eb2, inf_w, inf_b,
      xw1c, xb1, xw2, xb2, esr, mi, dx);

  node_kernel<<<NN / 16, 256, 0, stream>>>(
      hb, x, nw1c, nb1, nw2c, nb2, mi, dx, out);
}

// Round 4
// 276.929 us; speedup vs baseline: 1.4561x; 1.4561x over previous
//
#include <hip/hip_runtime.h>
#include <stdint.h>
#include <math.h>

// Problem constants
#define NN   20000
#define EE   320000
#define HH   128
#define MSTR 136            // h1/mij LDS row stride (u16)

typedef __attribute__((ext_vector_type(8)))  short          bf16x8;
typedef __attribute__((ext_vector_type(4)))  float          f32x4;
typedef __attribute__((ext_vector_type(16))) float          f32x16;
typedef unsigned short u16;
typedef unsigned int   u32;

// fp32 -> bf16 round-to-nearest-even
__device__ __forceinline__ u16 f2b(float f) {
  union { float f; unsigned int u; } v; v.f = f;
  return (u16)((v.u + 0x7fffu + ((v.u >> 16) & 1u)) >> 16);
}
__device__ __forceinline__ float b2f(unsigned int x) {
  union { float f; unsigned int u; } v; v.u = x << 16;
  return v.f;
}
__device__ __forceinline__ bf16x8 cvt8(float4 a, float4 b) {
  bf16x8 r;
  r[0] = (short)f2b(a.x); r[1] = (short)f2b(a.y);
  r[2] = (short)f2b(a.z); r[3] = (short)f2b(a.w);
  r[4] = (short)f2b(b.x); r[5] = (short)f2b(b.y);
  r[6] = (short)f2b(b.z); r[7] = (short)f2b(b.w);
  return r;
}
__device__ __forceinline__ bf16x8 pack8(const float* v) {
  bf16x8 r;
  #pragma unroll
  for (int j = 0; j < 8; ++j) r[j] = (short)f2b(v[j]);
  return r;
}

// packed bf16x2 atomic add (CDNA4 global_atomic_pk_add_bf16), fire-and-forget
__device__ __forceinline__ void pk_atomic_bf16(u16* addr, unsigned int data) {
  asm volatile("global_atomic_pk_add_bf16 %0, %1, off"
               :
               : "v"((unsigned long long)(uintptr_t)addr), "v"(data)
               : "memory");
}

// ---------------------------------------------------------------------------
// prep: (a) zero mi+dx+hist, (b) h -> bf16 (hb; used by BOTH edge gathers and
// node — bf16 gathers halve the h component of edge FETCH and delete the
// per-thread cvt8 VALU), (c) pack weights to bf16.
// 32-style (edge GEMMs, mfma 32x32x16): n = nt*32+(l&31), k = kc*16+(l>>5)*8+j
// 16-style (node GEMMs, mfma 16x16x32): n = nt*16+(l&15), k = kc*32+(l>>4)*8+j
// ew1 K-rows permuted to feat order (hi | hj | attr+rbf | pad).
// ---------------------------------------------------------------------------
__global__ void prep_kernel(const float* __restrict__ h,
                            const float* __restrict__ ew1, const float* __restrict__ ew2,
                            const float* __restrict__ xw1, const float* __restrict__ nw1,
                            const float* __restrict__ nw2,
                            u16* __restrict__ ew1c, u16* __restrict__ ew2c,
                            u16* __restrict__ xw1c, u16* __restrict__ nw1c,
                            u16* __restrict__ nw2c, float4* __restrict__ zbase,
                            u16* __restrict__ hb) {
  int idx = blockIdx.x * 256 + threadIdx.x;

  // zero mi (5120000 B) + dx (240000 B) + hist (80000 B) = 340000 float4s
  float4 z4 = {0.f, 0.f, 0.f, 0.f};
  #pragma unroll
  for (int i = 0; i < 3; ++i) {
    int j = idx + i * 122880;
    if (j < 340000) zbase[j] = z4;
  }
  // h -> bf16: 2,560,000 elems = 320,000 chunks of 8
  #pragma unroll
  for (int i = 0; i < 3; ++i) {
    int c = idx + i * 122880;
    if (c < 320000) {
      float4 a = *(const float4*)&h[(size_t)c * 8];
      float4 b = *(const float4*)&h[(size_t)c * 8 + 4];
      *(bf16x8*)&hb[(size_t)c * 8] = cvt8(a, b);
    }
  }

  int i2, style;
  u16* dst;
  const float* src;
  if (idx < 40960)       { i2 = idx;          dst = ew1c; src = ew1; style = 1; }
  else if (idx < 57344)  { i2 = idx - 40960;  dst = ew2c; src = ew2; style = 1; }
  else if (idx < 73728)  { i2 = idx - 57344;  dst = xw1c; src = xw1; style = 1; }
  else if (idx < 106496) { i2 = idx - 73728;  dst = nw1c; src = nw1; style = 0; }
  else if (idx < 122880) { i2 = idx - 106496; dst = nw2c; src = nw2; style = 0; }
  else return;

  int n, k;
  if (style) {
    int kc = i2 >> 11, rem = i2 & 2047, nt = rem >> 9, rem2 = rem & 511;
    int l = rem2 >> 3, j = rem2 & 7;
    n = nt * 32 + (l & 31);
    k = kc * 16 + (l >> 5) * 8 + j;
  } else {
    int kc = i2 >> 12, rem = i2 & 4095, nt = rem >> 9, rem2 = rem & 511;
    int l = rem2 >> 3, j = rem2 & 7;
    n = nt * 16 + (l & 15);
    k = kc * 32 + (l >> 4) * 8 + j;
  }
  float v;
  if (dst == ew1c) {
    if (k < 256)      v = src[(k + 48) * HH + n];   // hi|hj block
    else if (k < 304) v = src[(k - 256) * HH + n];  // attr|rbf block
    else              v = 0.0f;                     // pad (kc 19, unused)
  } else {
    v = src[k * HH + n];
  }
  dst[i2] = f2b(v);
}

// ---------------------------------------------------------------------------
// counting sort by dst, 3 PLAIN launches (the R3 cooperative fusion spent
// 135us spinning in grid.sync — reverted; these 3 total ~12us exec).
// ---------------------------------------------------------------------------
__global__ void hist_kernel(const int* __restrict__ edge_index,
                            u32* __restrict__ hist) {
  int e = blockIdx.x * 256 + threadIdx.x;
  if (e < EE) atomicAdd(&hist[edge_index[e]], 1u);
}

__global__ __launch_bounds__(1024) void scan_kernel(const u32* __restrict__ hist,
                                                    u32* __restrict__ cursor) {
  __shared__ u32 tot[1024];
  int t = threadIdx.x;
  int base = t * 20;                       // 1024*20 = 20480 >= NN
  u32 loc[20];
  u32 s = 0;
  #pragma unroll
  for (int i = 0; i < 20; ++i) {
    int d = base + i;
    u32 c = (d < NN) ? hist[d] : 0u;
    loc[i] = s; s += c;
  }
  tot[t] = s;
  __syncthreads();
  for (int off = 1; off < 1024; off <<= 1) {
    u32 v = (t >= off) ? tot[t - off] : 0u;
    __syncthreads();
    tot[t] += v;
    __syncthreads();
  }
  u32 ex = (t > 0) ? tot[t - 1] : 0u;
  #pragma unroll
  for (int i = 0; i < 20; ++i) {
    int d = base + i;
    if (d < NN) cursor[d] = ex + loc[i];
  }
}

// scatter packed records {dst | src<<15, eid} into dst-sorted slots so the
// edge kernel gets all per-row state with ONE 8-B sequential load.
__global__ void scatter_kernel(const int* __restrict__ edge_index,
                               u32* __restrict__ cursor,
                               uint2* __restrict__ esr) {
  int e = blockIdx.x * 256 + threadIdx.x;
  if (e < EE) {
    int d = edge_index[e];
    int s = edge_index[EE + e];
    u32 p = atomicAdd(&cursor[d], 1u);
    esr[p] = make_uint2((u32)d | ((u32)s << 15), (u32)e);
  }
}

// ---------------------------------------------------------------------------
// edge kernel: 128 dst-sorted slots/block, 4 waves, wave owns 32 rows x 128
// cols, mfma 32x32x16. BARRIER-FREE: each lane loads its row's packed record
// (8 B sequential); all LDS traffic is wave-private, so the 4 waves run fully
// decoupled. h gathers now read hb (bf16): identical numerics (same RNE cvt,
// done once in prep), half the gather bytes, no cvt8 VALU, fewer live VGPRs.
// launch_bounds(256,4): 4 blocks/CU (LDS 38400*4=153.6K fits).
// mi/dx: fp32 run-aggregation over sorted runs, ~1 pk-atomic burst per run.
// ---------------------------------------------------------------------------
__global__ __launch_bounds__(256, 4) void edge_kernel(
    const u16* __restrict__ hb, const float* __restrict__ x,
    const float* __restrict__ edge_attr,
    const u16* __restrict__ ew1c, const float* __restrict__ eb1,
    const u16* __restrict__ ew2c, const float* __restrict__ eb2,
    const float* __restrict__ inf_w, const float* __restrict__ inf_b,
    const u16* __restrict__ xw1c, const float* __restrict__ xb1,
    const float* __restrict__ xw2, const float* __restrict__ xb2,
    const uint2* __restrict__ esr,
    u16* __restrict__ mi, float* __restrict__ dx) {
  __shared__ u16 h1_s[128 * MSTR];     // 34816 B: GEMM1 out, then mij overlay
  __shared__ float relx_s[128][4];     //  2048 B
  __shared__ int dst_s[128];           //   512 B
  __shared__ float eij_s[4][32];       //   512 B
  __shared__ float xg_s[4][32];        //   512 B

  const int t   = threadIdx.x;
  const int w   = t >> 6;
  const int l   = t & 63;
  const int l31 = l & 31;
  const int hh  = l >> 5;              // k-half
  const int e0  = blockIdx.x * 128;
  const int myrow = w * 32 + l31;      // local row 0..127

  // ---- phase A (barrier-free): per-lane packed record + rel_x ----
  uint2 rec = esr[e0 + myrow];
  const int dstv = (int)(rec.x & 0x7FFFu);
  const int srcv = (int)((rec.x >> 15) & 0x7FFFu);
  const int eid  = (int)rec.y;

  float rx = x[dstv * 3 + 0] - x[srcv * 3 + 0];
  float ry = x[dstv * 3 + 1] - x[srcv * 3 + 1];
  float rz = x[dstv * 3 + 2] - x[srcv * 3 + 2];
  const float dn = sqrtf(rx * rx + ry * ry + rz * rz);
  if (hh == 0) {
    dst_s[myrow] = dstv;
    relx_s[myrow][0] = rx; relx_s[myrow][1] = ry;
    relx_s[myrow][2] = rz; relx_s[myrow][3] = dn;
  }
  // no __syncthreads(): all later LDS reads are of this wave's own band;
  // per-wave LDS ordering + compiler lgkmcnt waits cover the RAW deps.

  f32x16 acc[4];
  #pragma unroll
  for (int nt = 0; nt < 4; ++nt)
    #pragma unroll
    for (int i = 0; i < 16; ++i) acc[nt][i] = 0.f;

  // ---- GEMM1 phase hi (feat k 0..127 = h[dst]; sorted -> few rows/wave) ----
  {
    const u16* hp = hb + (size_t)dstv * HH;
    bf16x8 af[8];
    #pragma unroll
    for (int kc = 0; kc < 8; ++kc)
      af[kc] = *(const bf16x8*)&hp[kc * 16 + hh * 8];
    #pragma unroll
    for (int kc = 0; kc < 8; ++kc) {
      const u16* bp = ew1c + (kc * 4) * 512 + l * 8;
      #pragma unroll
      for (int nt = 0; nt < 4; ++nt) {
        bf16x8 b = *(const bf16x8*)(bp + nt * 512);
        acc[nt] = __builtin_amdgcn_mfma_f32_32x32x16_bf16(af[kc], b, acc[nt], 0, 0, 0);
      }
    }
  }
  // ---- GEMM1 phase hj (feat k 128..255 = h[src]) ----
  {
    const u16* hp = hb + (size_t)srcv * HH;
    bf16x8 af[8];
    #pragma unroll
    for (int kc = 0; kc < 8; ++kc)
      af[kc] = *(const bf16x8*)&hp[kc * 16 + hh * 8];
    #pragma unroll
    for (int kc = 0; kc < 8; ++kc) {
      const u16* bp = ew1c + ((8 + kc) * 4) * 512 + l * 8;
      #pragma unroll
      for (int nt = 0; nt < 4; ++nt) {
        bf16x8 b = *(const bf16x8*)(bp + nt * 512);
        acc[nt] = __builtin_amdgcn_mfma_f32_32x32x16_bf16(af[kc], b, acc[nt], 0, 0, 0);
      }
    }
  }
  // ---- GEMM1 phase attr+rbf (feat k 256..303; kc 16..18) ----
  {
    const float step  = 100.0f / 19.0f;
    const float coeff = -0.5f / (step * step);
    const float* ap   = edge_attr + (size_t)eid * 28;
    float v0[8], v1[8], v2[8];
    if (hh == 0) {
      float4 a0 = *(const float4*)&ap[0],  a1 = *(const float4*)&ap[4];
      float4 a2 = *(const float4*)&ap[16], a3 = *(const float4*)&ap[20];
      v0[0]=a0.x; v0[1]=a0.y; v0[2]=a0.z; v0[3]=a0.w;
      v0[4]=a1.x; v0[5]=a1.y; v0[6]=a1.z; v0[7]=a1.w;
      v1[0]=a2.x; v1[1]=a2.y; v1[2]=a2.z; v1[3]=a2.w;
      v1[4]=a3.x; v1[5]=a3.y; v1[6]=a3.z; v1[7]=a3.w;
      #pragma unroll
      for (int j = 0; j < 8; ++j) {           // rbf 4..11
        float dd = dn - (float)(4 + j) * step;
        v2[j] = __expf(coeff * dd * dd);
      }
    } else {
      float4 a0 = *(const float4*)&ap[8],  a1 = *(const float4*)&ap[12];
      float4 a2 = *(const float4*)&ap[24];
      v0[0]=a0.x; v0[1]=a0.y; v0[2]=a0.z; v0[3]=a0.w;
      v0[4]=a1.x; v0[5]=a1.y; v0[6]=a1.z; v0[7]=a1.w;
      v1[0]=a2.x; v1[1]=a2.y; v1[2]=a2.z; v1[3]=a2.w;
      #pragma unroll
      for (int j = 0; j < 4; ++j) {           // rbf 0..3
        float dd = dn - (float)j * step;
        v1[4 + j] = __expf(coeff * dd * dd);
      }
      #pragma unroll
      for (int j = 0; j < 8; ++j) {           // rbf 12..19
        float dd = dn - (float)(12 + j) * step;
        v2[j] = __expf(coeff * dd * dd);
      }
    }
    bf16x8 afr[3];
    afr[0] = pack8(v0); afr[1] = pack8(v1); afr[2] = pack8(v2);
    #pragma unroll
    for (int kc = 0; kc < 3; ++kc) {
      const u16* bp = ew1c + ((16 + kc) * 4) * 512 + l * 8;
      #pragma unroll
      for (int nt = 0; nt < 4; ++nt) {
        bf16x8 b = *(const bf16x8*)(bp + nt * 512);
        acc[nt] = __builtin_amdgcn_mfma_f32_32x32x16_bf16(afr[kc], b, acc[nt], 0, 0, 0);
      }
    }
  }
  // ---- GEMM1 epilogue: relu(+eb1) -> h1_s (wave-private rows) ----
  #pragma unroll
  for (int nt = 0; nt < 4; ++nt) {
    float bb = eb1[nt * 32 + l31];
    #pragma unroll
    for (int i = 0; i < 16; ++i) {
      float v = acc[nt][i] + bb; v = v > 0.f ? v : 0.f;
      int row = (i & 3) + 8 * (i >> 2) + 4 * hh;
      h1_s[(w * 32 + row) * MSTR + nt * 32 + l31] = f2b(v);
    }
  }

  // ---- GEMM2: A = h1 (own band, no barrier), B = ew2c ----
  bf16x8 a2[8];
  #pragma unroll
  for (int kc = 0; kc < 8; ++kc)
    a2[kc] = *(const bf16x8*)&h1_s[myrow * MSTR + kc * 16 + hh * 8];
  #pragma unroll
  for (int nt = 0; nt < 4; ++nt)
    #pragma unroll
    for (int i = 0; i < 16; ++i) acc[nt][i] = 0.f;
  #pragma unroll
  for (int kc = 0; kc < 8; ++kc) {
    const u16* bp = ew2c + (kc * 4) * 512 + l * 8;
    #pragma unroll
    for (int nt = 0; nt < 4; ++nt) {
      bf16x8 b = *(const bf16x8*)(bp + nt * 512);
      acc[nt] = __builtin_amdgcn_mfma_f32_32x32x16_bf16(a2[kc], b, acc[nt], 0, 0, 0);
    }
  }
  // ---- GEMM2 epilogue: mij = relu(+eb2) -> h1_s overlay; eij partials ----
  float p[16];
  #pragma unroll
  for (int i = 0; i < 16; ++i) p[i] = 0.f;
  #pragma unroll
  for (int nt = 0; nt < 4; ++nt) {
    float bb = eb2[nt * 32 + l31];
    float iw = inf_w[nt * 32 + l31];
    #pragma unroll
    for (int i = 0; i < 16; ++i) {
      float v = acc[nt][i] + bb; v = v > 0.f ? v : 0.f;
      p[i] += v * iw;
      int row = (i & 3) + 8 * (i >> 2) + 4 * hh;
      h1_s[(w * 32 + row) * MSTR + nt * 32 + l31] = f2b(v);
    }
  }
  // eij: reduce over 32 cols (xor, width 32), sigmoid; stash per-row to LDS
  {
    float ib = inf_b[0];
    #pragma unroll
    for (int m = 1; m < 32; m <<= 1)
      #pragma unroll
      for (int i = 0; i < 16; ++i) p[i] += __shfl_xor(p[i], m, 32);
    #pragma unroll
    for (int i = 0; i < 16; ++i)
      p[i] = 1.0f / (1.0f + __expf(-(p[i] + ib)));   // p = eij per row-slot
    if (l31 == 0) {
      #pragma unroll
      for (int i = 0; i < 16; ++i) {
        int row = (i & 3) + 8 * (i >> 2) + 4 * hh;
        eij_s[w][row] = p[i];
      }
    }
  }

  // ---- GEMM3: A = mij (own band), B = xw1c ----
  bf16x8 a3[8];
  #pragma unroll
  for (int kc = 0; kc < 8; ++kc)
    a3[kc] = *(const bf16x8*)&h1_s[myrow * MSTR + kc * 16 + hh * 8];
  #pragma unroll
  for (int nt = 0; nt < 4; ++nt)
    #pragma unroll
    for (int i = 0; i < 16; ++i) acc[nt][i] = 0.f;
  #pragma unroll
  for (int kc = 0; kc < 8; ++kc) {
    const u16* bp = xw1c + (kc * 4) * 512 + l * 8;
    #pragma unroll
    for (int nt = 0; nt < 4; ++nt) {
      bf16x8 b = *(const bf16x8*)(bp + nt * 512);
      acc[nt] = __builtin_amdgcn_mfma_f32_32x32x16_bf16(a3[kc], b, acc[nt], 0, 0, 0);
    }
  }
  // ---- xg = relu(+xb1) @ xw2 + xb2, reduced over cols; stash to LDS ----
  float p2[16];
  #pragma unroll
  for (int i = 0; i < 16; ++i) p2[i] = 0.f;
  #pragma unroll
  for (int nt = 0; nt < 4; ++nt) {
    float bb = xb1[nt * 32 + l31];
    float xv = xw2[nt * 32 + l31];
    #pragma unroll
    for (int i = 0; i < 16; ++i) {
      float v = acc[nt][i] + bb; v = v > 0.f ? v : 0.f;
      p2[i] += v * xv;
    }
  }
  {
    float xb2_0 = xb2[0];
    #pragma unroll
    for (int m = 1; m < 32; m <<= 1)
      #pragma unroll
      for (int i = 0; i < 16; ++i) p2[i] += __shfl_xor(p2[i], m, 32);
    #pragma unroll
    for (int i = 0; i < 16; ++i) p2[i] += xb2_0;
    if (l31 == 0) {
      #pragma unroll
      for (int i = 0; i < 16; ++i) {
        int row = (i & 3) + 8 * (i >> 2) + 4 * hh;
        xg_s[w][row] = p2[i];
      }
    }
  }

  // ---- mi: run-aggregated flush over the wave's own 32 sorted rows. Lane
  // owns col-pair (2l,2l+1); fp32-accumulate bf16(mij)*eij per equal-dst run;
  // one pk-atomic burst per run boundary (wave-uniform branch). r==31 always
  // flushes, so no cross-band LDS read (barrier-free safe). ----
  {
    float s0 = 0.f, s1 = 0.f;
    for (int r = 0; r < 32; ++r) {
      int gr = w * 32 + r;
      unsigned int pr = *(const unsigned int*)&h1_s[gr * MSTR + 2 * l];
      float e = eij_s[w][r];
      s0 += b2f(pr & 0xffffu) * e;
      s1 += b2f(pr >> 16) * e;
      bool flush = (r == 31) || (dst_s[gr + 1] != dst_s[gr]);
      if (flush) {
        unsigned int packed = (unsigned int)f2b(s0) | ((unsigned int)f2b(s1) << 16);
        pk_atomic_bf16(mi + (size_t)dst_s[gr] * HH + 2 * l, packed);
        s0 = 0.f; s1 = 0.f;
      }
    }
  }
  // ---- dx: run-aggregated, 3 lanes/wave scan own band ----
  if (l < 3) {
    float sd = 0.f;
    for (int r = 0; r < 32; ++r) {
      int gr = w * 32 + r;
      sd += relx_s[gr][l] * xg_s[w][r];
      if (r == 31 || dst_s[gr + 1] != dst_s[gr]) {
        atomicAdd(&dx[(size_t)dst_s[gr] * 3 + l], sd);
        sd = 0.f;
      }
    }
  }
}

// ---------------------------------------------------------------------------
// node kernel: 16 rows/block, 1250 blocks; waves split N. h read via hb
// (bf16, direct contiguous loads). 16x16x32 MFMA.
// ---------------------------------------------------------------------------
__global__ __launch_bounds__(256, 6) void node_kernel(
    const u16* __restrict__ hb, const float* __restrict__ x,
    const u16* __restrict__ nw1c, const float* __restrict__ nb1,
    const u16* __restrict__ nw2c, const float* __restrict__ nb2,
    const u16* __restrict__ mi, const float* __restrict__ dx,
    float* __restrict__ out) {
  __shared__ u16 h1_s[16 * MSTR];

  const int t   = threadIdx.x;
  const int w   = t >> 6;
  const int l   = t & 63;
  const int l15 = l & 15;
  const int q   = l >> 4;
  const int r0  = blockIdx.x * 16;
  const int gr  = r0 + l15;

  const u16* mp = mi + (size_t)gr * HH;
  const u16* hp = hb + (size_t)gr * HH;
  bf16x8 afrag[8];
  #pragma unroll
  for (int c = 0; c < 4; ++c) {
    afrag[c]     = *(const bf16x8*)&mp[c * 32 + q * 8];
    afrag[4 + c] = *(const bf16x8*)&hp[c * 32 + q * 8];
  }

  f32x4 acc[2];
  acc[0] = (f32x4){0.f, 0.f, 0.f, 0.f};
  acc[1] = (f32x4){0.f, 0.f, 0.f, 0.f};
  #pragma unroll
  for (int kc = 0; kc < 8; ++kc) {
    const u16* bp = nw1c + (kc << 12) + l * 8;
    #pragma unroll
    for (int i = 0; i < 2; ++i) {
      bf16x8 b = *(const bf16x8*)(bp + (2 * w + i) * 512);
      acc[i] = __builtin_amdgcn_mfma_f32_16x16x32_bf16(afrag[kc], b, acc[i], 0, 0, 0);
    }
  }
  #pragma unroll
  for (int i = 0; i < 2; ++i) {
    int nt = 2 * w + i;
    float b1 = nb1[nt * 16 + l15];
    #pragma unroll
    for (int r = 0; r < 4; ++r) {
      float v = acc[i][r] + b1; v = v > 0.f ? v : 0.f;
      h1_s[(q * 4 + r) * MSTR + nt * 16 + l15] = f2b(v);
    }
  }
  __syncthreads();

  bf16x8 a2[4];
  #pragma unroll
  for (int kc = 0; kc < 4; ++kc)
    a2[kc] = *(const bf16x8*)&h1_s[l15 * MSTR + kc * 32 + q * 8];
  acc[0] = (f32x4){0.f, 0.f, 0.f, 0.f};
  acc[1] = (f32x4){0.f, 0.f, 0.f, 0.f};
  #pragma unroll
  for (int kc = 0; kc < 4; ++kc) {
    const u16* bp = nw2c + (kc << 12) + l * 8;
    #pragma unroll
    for (int i = 0; i < 2; ++i) {
      bf16x8 b = *(const bf16x8*)(bp + (2 * w + i) * 512);
      acc[i] = __builtin_amdgcn_mfma_f32_16x16x32_bf16(a2[kc], b, acc[i], 0, 0, 0);
    }
  }
  #pragma unroll
  for (int i = 0; i < 2; ++i) {
    int nt = 2 * w + i;
    float b2 = nb2[nt * 16 + l15];
    #pragma unroll
    for (int r = 0; r < 4; ++r)
      out[(size_t)(r0 + q * 4 + r) * HH + nt * 16 + l15] = acc[i][r] + b2;
  }
  if (t < 48) {
    int rr = t / 3, dim = t % 3;
    int gr2 = r0 + rr;
    out[(size_t)NN * HH + (size_t)gr2 * 3 + dim] =
        x[(size_t)gr2 * 3 + dim] + dx[(size_t)gr2 * 3 + dim] * (1.0f / (float)EE);
  }
}

// ---------------------------------------------------------------------------
// launch: 6 dispatches (prep, hist, scan, scatter, edge, node)
// ---------------------------------------------------------------------------
extern "C" void kernel_launch(void* const* d_in, const int* in_sizes, int n_in,
                              void* d_out, int out_size, void* d_ws, size_t ws_size,
                              hipStream_t stream) {
  const float* h         = (const float*)d_in[0];
  const float* x         = (const float*)d_in[1];
  const float* edge_attr = (const float*)d_in[2];
  const float* ew1 = (const float*)d_in[3];
  const float* eb1 = (const float*)d_in[4];
  const float* ew2 = (const float*)d_in[5];
  const float* eb2 = (const float*)d_in[6];
  const float* inf_w = (const float*)d_in[7];
  const float* inf_b = (const float*)d_in[8];
  const float* nw1 = (const float*)d_in[9];
  const float* nb1 = (const float*)d_in[10];
  const float* nw2 = (const float*)d_in[11];
  const float* nb2 = (const float*)d_in[12];
  const float* xw1 = (const float*)d_in[13];
  const float* xb1 = (const float*)d_in[14];
  const float* xw2 = (const float*)d_in[15];
  const float* xb2 = (const float*)d_in[16];
  const int* edge_index = (const int*)d_in[17];
  float* out = (float*)d_out;

  char* wsb = (char*)d_ws;
  u16*   ew1c = (u16*)(wsb + 0);            //   81920 B (32-pack)
  u16*   ew2c = (u16*)(wsb + 81920);        //   32768 B (32-pack)
  u16*   xw1c = (u16*)(wsb + 114688);       //   32768 B (32-pack)
  u16*   nw1c = (u16*)(wsb + 147456);       //   65536 B (16-pack)
  u16*   nw2c = (u16*)(wsb + 212992);       //   32768 B (16-pack)
  u16*   mi   = (u16*)(wsb + 245760);       //  5120000 B (bf16)
  float* dx   = (float*)(wsb + 5365760);    //   240000 B
  u32*   hist = (u32*)(wsb + 5605760);      //    80000 B (zeroed by prep)
  u16*   hb   = (u16*)(wsb + 5685760);      //  5120000 B (bf16 h)
  u32*   cursor   = (u32*)(wsb + 10805760); //    80000 B
  uint2* esr      = (uint2*)(wsb + 10885760); // 2560000 B -> 13445760 total

  // prep zeroes mi+dx+hist and converts h -> hb
  prep_kernel<<<480, 256, 0, stream>>>(
      h, ew1, ew2, xw1, nw1, nw2, ew1c, ew2c, xw1c, nw1c, nw2c,
      (float4*)(wsb + 245760), hb);

  // counting sort of edges by dst (3 small plain launches)
  hist_kernel<<<EE / 256, 256, 0, stream>>>(edge_index, hist);
  scan_kernel<<<1, 1024, 0, stream>>>(hist, cursor);
  scatter_kernel<<<EE / 256, 256, 0, stream>>>(edge_index, cursor, esr);

  edge_kernel<<<EE / 128, 256, 0, stream>>>(
      hb, x, edge_attr, ew1c, eb1, ew2c, eb2, inf_w, inf_b,
      xw1c, xb1, xw2, xb2, esr, mi, dx);

  node_kernel<<<NN / 16, 256, 0, stream>>>(
      hb, x, nw1c, nb1, nw2c, nb2, mi, dx, out);
}